// Round 1
// baseline (524.068 us; speedup 1.0000x reference)
//
#include <hip/hip_runtime.h>

#define BB 16
#define SS 4096
#define HH 1024
#define SSPLIT 64

__device__ __forceinline__ float fast_tanh(float x) {
    // clamp so exp never overflows to inf (tanh saturated anyway)
    x = fminf(fmaxf(x, -15.0f), 15.0f);
    float e = __expf(-2.0f * x);
    return (1.0f - e) * __builtin_amdgcn_rcpf(1.0f + e);
}

__device__ __forceinline__ float wave_reduce_sum(float v) {
#pragma unroll
    for (int off = 32; off > 0; off >>= 1) v += __shfl_xor(v, off, 64);
    return v;
}

// dec_fea[b,h] = sum_k s_t_hat[b,k] * W_dec[h,k] + b_dec[h]
// one wave per (b,h); float4 coalesced loads; wave reduce
__global__ __launch_bounds__(256) void dec_fea_kernel(
    const float* __restrict__ s_t_hat, const float* __restrict__ W_dec,
    const float* __restrict__ b_dec, float* __restrict__ dec_fea)
{
    int wave = (blockIdx.x * blockDim.x + threadIdx.x) >> 6;  // 0..B*H-1
    int lane = threadIdx.x & 63;
    int b = wave >> 10;
    int h = wave & (HH - 1);
    const float4* st4 = (const float4*)(s_t_hat + (size_t)b * HH);
    const float4* wd4 = (const float4*)(W_dec + (size_t)h * HH);
    float acc = 0.0f;
#pragma unroll
    for (int j = 0; j < 4; ++j) {
        int idx = lane + 64 * j;
        float4 a = st4[idx];
        float4 w = wd4[idx];
        acc += a.x * w.x + a.y * w.y + a.z * w.z + a.w * w.w;
    }
    acc = wave_reduce_sum(acc);
    if (lane == 0) dec_fea[wave] = acc + b_dec[h];
}

// scores[row] = sum_h tanh(ef[row,h] + dec_fea[b,h] + cov[row]*W_c[h]) * v[h]
// one wave per row (row = b*S+s); 4 x float4 per lane, fully coalesced
__global__ __launch_bounds__(256) void scores_kernel(
    const float* __restrict__ ef, const float* __restrict__ dec_fea,
    const float* __restrict__ cov, const float* __restrict__ W_c,
    const float* __restrict__ v, float* __restrict__ scores)
{
    int row = (blockIdx.x * blockDim.x + threadIdx.x) >> 6;  // 0..B*S-1
    int lane = threadIdx.x & 63;
    int b = row >> 12;  // S = 4096
    float cv = cov[row];
    const float4* ef4 = (const float4*)(ef + (size_t)row * HH);
    const float4* de4 = (const float4*)(dec_fea + (size_t)b * HH);
    const float4* wc4 = (const float4*)W_c;
    const float4* v4  = (const float4*)v;
    float acc = 0.0f;
#pragma unroll
    for (int j = 0; j < 4; ++j) {
        int idx = lane + 64 * j;
        float4 x  = ef4[idx];
        float4 d  = de4[idx];
        float4 w  = wc4[idx];
        float4 vv = v4[idx];
        acc += fast_tanh(x.x + d.x + cv * w.x) * vv.x;
        acc += fast_tanh(x.y + d.y + cv * w.y) * vv.y;
        acc += fast_tanh(x.z + d.z + cv * w.z) * vv.z;
        acc += fast_tanh(x.w + d.w + cv * w.w) * vv.w;
    }
    acc = wave_reduce_sum(acc);
    if (lane == 0) scores[row] = acc;
}

// masked softmax with renormalization, per batch row; also zeroes c_t
// grid = B blocks, 1024 threads (each thread owns 4 consecutive s)
__global__ __launch_bounds__(1024) void softmax_kernel(
    const float* __restrict__ scores, const float* __restrict__ mask,
    float* __restrict__ attn1, float* __restrict__ attn2,
    float* __restrict__ c_t)
{
    int b = blockIdx.x;
    int tid = threadIdx.x;
    // zero-init c_t for the atomic accumulation in context_kernel
    c_t[b * HH + tid] = 0.0f;

    const float4* s4 = (const float4*)(scores + (size_t)b * SS);
    const float4* m4 = (const float4*)(mask + (size_t)b * SS);
    float4 sc = s4[tid];
    float4 mk = m4[tid];

    __shared__ float redA[16];
    __shared__ float redB[16];
    int wid = tid >> 6, lane = tid & 63;

    // block max
    float mx = fmaxf(fmaxf(sc.x, sc.y), fmaxf(sc.z, sc.w));
#pragma unroll
    for (int off = 32; off > 0; off >>= 1) mx = fmaxf(mx, __shfl_xor(mx, off, 64));
    if (lane == 0) redA[wid] = mx;
    __syncthreads();
    float bm = redA[0];
#pragma unroll
    for (int i = 1; i < 16; ++i) bm = fmaxf(bm, redA[i]);
    __syncthreads();

    float4 e;
    e.x = __expf(sc.x - bm);
    e.y = __expf(sc.y - bm);
    e.z = __expf(sc.z - bm);
    e.w = __expf(sc.w - bm);
    float4 t;
    t.x = e.x * mk.x; t.y = e.y * mk.y; t.z = e.z * mk.z; t.w = e.w * mk.w;

    float se = wave_reduce_sum(e.x + e.y + e.z + e.w);
    float st = wave_reduce_sum(t.x + t.y + t.z + t.w);
    if (lane == 0) { redA[wid] = se; redB[wid] = st; }
    __syncthreads();
    float tot_e = 0.0f, tot_t = 0.0f;
#pragma unroll
    for (int i = 0; i < 16; ++i) { tot_e += redA[i]; tot_t += redB[i]; }

    // attn_i = (e_i*m_i/tot_e) / (tot_t/tot_e + 1e-20)   (exact reference order)
    float inv = 1.0f / tot_e;
    float r = 1.0f / (tot_t * inv + 1e-20f);
    float scale = inv * r;
    float4 a;
    a.x = t.x * scale; a.y = t.y * scale; a.z = t.z * scale; a.w = t.w * scale;
    ((float4*)(attn1 + (size_t)b * SS))[tid] = a;
    ((float4*)(attn2 + (size_t)b * SS))[tid] = a;
}

// c_t[b,h] += sum_{s in chunk} attn[b,s] * eo[b,s,h]
// grid (SSPLIT, B), 256 threads; each thread owns a float4 of H (tid*4)
__global__ __launch_bounds__(256) void context_kernel(
    const float* __restrict__ eo, const float* __restrict__ attn,
    float* __restrict__ c_t)
{
    int b = blockIdx.y;
    int s0 = blockIdx.x * (SS / SSPLIT);
    int tid = threadIdx.x;
    const float4* eo4 = (const float4*)(eo + ((size_t)b * SS + s0) * HH);
    const float* at = attn + (size_t)b * SS + s0;
    float4 acc = {0.0f, 0.0f, 0.0f, 0.0f};
#pragma unroll 4
    for (int s = 0; s < SS / SSPLIT; ++s) {
        float a = at[s];
        float4 x = eo4[(size_t)s * 256 + tid];
        acc.x += a * x.x; acc.y += a * x.y; acc.z += a * x.z; acc.w += a * x.w;
    }
    float* dst = c_t + (size_t)b * HH + tid * 4;
    atomicAdd(dst + 0, acc.x);
    atomicAdd(dst + 1, acc.y);
    atomicAdd(dst + 2, acc.z);
    atomicAdd(dst + 3, acc.w);
}

extern "C" void kernel_launch(void* const* d_in, const int* in_sizes, int n_in,
                              void* d_out, int out_size, void* d_ws, size_t ws_size,
                              hipStream_t stream)
{
    const float* s_t_hat  = (const float*)d_in[0];
    const float* enc_out  = (const float*)d_in[1];
    const float* enc_feat = (const float*)d_in[2];
    const float* mask     = (const float*)d_in[3];
    const float* cov      = (const float*)d_in[4];
    const float* W_dec    = (const float*)d_in[5];
    const float* b_dec    = (const float*)d_in[6];
    const float* W_c      = (const float*)d_in[7];
    const float* v        = (const float*)d_in[8];

    float* out    = (float*)d_out;
    float* c_t    = out;                    // B*H
    float* attn1  = out + BB * HH;          // B*S
    float* attn2  = attn1 + BB * SS;        // B*S
    float* scores = attn2 + BB * SS;        // B*S

    float* dec_fea = (float*)d_ws;          // B*H floats scratch

    dec_fea_kernel<<<dim3(BB * HH / 4), 256, 0, stream>>>(s_t_hat, W_dec, b_dec, dec_fea);
    scores_kernel<<<dim3(BB * SS / 4), 256, 0, stream>>>(enc_feat, dec_fea, cov, W_c, v, scores);
    softmax_kernel<<<dim3(BB), 1024, 0, stream>>>(scores, mask, attn1, attn2, c_t);
    context_kernel<<<dim3(SSPLIT, BB), 256, 0, stream>>>(enc_out, attn1, c_t);
}

// Round 2
// 521.517 us; speedup vs baseline: 1.0049x; 1.0049x over previous
//
#include <hip/hip_runtime.h>

#define BB 16
#define SS 4096
#define HH 1024
#define SSPLIT 64

__device__ __forceinline__ float fast_tanh(float x) {
    // clamp so exp never overflows to inf (tanh saturated anyway)
    x = fminf(fmaxf(x, -15.0f), 15.0f);
    float e = __expf(-2.0f * x);
    return (1.0f - e) * __builtin_amdgcn_rcpf(1.0f + e);
}

__device__ __forceinline__ float wave_reduce_sum(float v) {
#pragma unroll
    for (int off = 32; off > 0; off >>= 1) v += __shfl_xor(v, off, 64);
    return v;
}

// dec_fea[b,h] = sum_k s_t_hat[b,k] * W_dec[h,k] + b_dec[h]
// one wave per (b,h); float4 coalesced loads; wave reduce
__global__ __launch_bounds__(256) void dec_fea_kernel(
    const float* __restrict__ s_t_hat, const float* __restrict__ W_dec,
    const float* __restrict__ b_dec, float* __restrict__ dec_fea)
{
    int wave = (blockIdx.x * blockDim.x + threadIdx.x) >> 6;  // 0..B*H-1
    int lane = threadIdx.x & 63;
    int b = wave >> 10;
    int h = wave & (HH - 1);
    const float4* st4 = (const float4*)(s_t_hat + (size_t)b * HH);
    const float4* wd4 = (const float4*)(W_dec + (size_t)h * HH);
    float acc = 0.0f;
#pragma unroll
    for (int j = 0; j < 4; ++j) {
        int idx = lane + 64 * j;
        float4 a = st4[idx];
        float4 w = wd4[idx];
        acc += a.x * w.x + a.y * w.y + a.z * w.z + a.w * w.w;
    }
    acc = wave_reduce_sum(acc);
    if (lane == 0) dec_fea[wave] = acc + b_dec[h];
}

// scores[row] = sum_h tanh(ef[row,h] + dec_fea[b,h] + cov[row]*W_c[h]) * v[h]
// one wave per row (row = b*S+s); 4 x float4 per lane, fully coalesced
__global__ __launch_bounds__(256) void scores_kernel(
    const float* __restrict__ ef, const float* __restrict__ dec_fea,
    const float* __restrict__ cov, const float* __restrict__ W_c,
    const float* __restrict__ v, float* __restrict__ scores)
{
    int row = (blockIdx.x * blockDim.x + threadIdx.x) >> 6;  // 0..B*S-1
    int lane = threadIdx.x & 63;
    int b = row >> 12;  // S = 4096
    float cv = cov[row];
    const float4* ef4 = (const float4*)(ef + (size_t)row * HH);
    const float4* de4 = (const float4*)(dec_fea + (size_t)b * HH);
    const float4* wc4 = (const float4*)W_c;
    const float4* v4  = (const float4*)v;
    float acc = 0.0f;
#pragma unroll
    for (int j = 0; j < 4; ++j) {
        int idx = lane + 64 * j;
        float4 x  = ef4[idx];
        float4 d  = de4[idx];
        float4 w  = wc4[idx];
        float4 vv = v4[idx];
        acc += fast_tanh(x.x + d.x + cv * w.x) * vv.x;
        acc += fast_tanh(x.y + d.y + cv * w.y) * vv.y;
        acc += fast_tanh(x.z + d.z + cv * w.z) * vv.z;
        acc += fast_tanh(x.w + d.w + cv * w.w) * vv.w;
    }
    acc = wave_reduce_sum(acc);
    if (lane == 0) scores[row] = acc;
}

// masked softmax with renormalization, per batch row
// grid = B blocks, 1024 threads (each thread owns 4 consecutive s)
__global__ __launch_bounds__(1024) void softmax_kernel(
    const float* __restrict__ scores, const float* __restrict__ mask,
    float* __restrict__ attn1, float* __restrict__ attn2)
{
    int b = blockIdx.x;
    int tid = threadIdx.x;

    const float4* s4 = (const float4*)(scores + (size_t)b * SS);
    const float4* m4 = (const float4*)(mask + (size_t)b * SS);
    float4 sc = s4[tid];
    float4 mk = m4[tid];

    __shared__ float redA[16];
    __shared__ float redB[16];
    int wid = tid >> 6, lane = tid & 63;

    // block max
    float mx = fmaxf(fmaxf(sc.x, sc.y), fmaxf(sc.z, sc.w));
#pragma unroll
    for (int off = 32; off > 0; off >>= 1) mx = fmaxf(mx, __shfl_xor(mx, off, 64));
    if (lane == 0) redA[wid] = mx;
    __syncthreads();
    float bm = redA[0];
#pragma unroll
    for (int i = 1; i < 16; ++i) bm = fmaxf(bm, redA[i]);
    __syncthreads();

    float4 e;
    e.x = __expf(sc.x - bm);
    e.y = __expf(sc.y - bm);
    e.z = __expf(sc.z - bm);
    e.w = __expf(sc.w - bm);
    float4 t;
    t.x = e.x * mk.x; t.y = e.y * mk.y; t.z = e.z * mk.z; t.w = e.w * mk.w;

    float se = wave_reduce_sum(e.x + e.y + e.z + e.w);
    float st = wave_reduce_sum(t.x + t.y + t.z + t.w);
    if (lane == 0) { redA[wid] = se; redB[wid] = st; }
    __syncthreads();
    float tot_e = 0.0f, tot_t = 0.0f;
#pragma unroll
    for (int i = 0; i < 16; ++i) { tot_e += redA[i]; tot_t += redB[i]; }

    // attn_i = (e_i*m_i/tot_e) / (tot_t/tot_e + 1e-20)   (exact reference order)
    float inv = 1.0f / tot_e;
    float r = 1.0f / (tot_t * inv + 1e-20f);
    float scale = inv * r;
    float4 a;
    a.x = t.x * scale; a.y = t.y * scale; a.z = t.z * scale; a.w = t.w * scale;
    ((float4*)(attn1 + (size_t)b * SS))[tid] = a;
    ((float4*)(attn2 + (size_t)b * SS))[tid] = a;
}

// partials[split][b][h] = sum_{s in chunk} attn[b,s] * eo[b,s,h]
// grid (SSPLIT, B), 256 threads; each thread owns a float4 of H (tid*4)
// NO atomics — deterministic partial sums to workspace.
__global__ __launch_bounds__(256) void context_partial_kernel(
    const float* __restrict__ eo, const float* __restrict__ attn,
    float* __restrict__ partials)
{
    int b = blockIdx.y;
    int s0 = blockIdx.x * (SS / SSPLIT);
    int tid = threadIdx.x;
    const float4* eo4 = (const float4*)(eo + ((size_t)b * SS + s0) * HH);
    const float* at = attn + (size_t)b * SS + s0;
    float4 acc = {0.0f, 0.0f, 0.0f, 0.0f};
#pragma unroll 8
    for (int s = 0; s < SS / SSPLIT; ++s) {
        float a = at[s];
        float4 x = eo4[(size_t)s * 256 + tid];
        acc.x += a * x.x; acc.y += a * x.y; acc.z += a * x.z; acc.w += a * x.w;
    }
    float4* dst = (float4*)(partials + ((size_t)blockIdx.x * BB + b) * HH);
    dst[tid] = acc;
}

// c_t[b,h] = sum_split partials[split][b][h]
// grid = B*H/1024 blocks x 256 threads, float4 per thread
__global__ __launch_bounds__(256) void context_reduce_kernel(
    const float* __restrict__ partials, float* __restrict__ c_t)
{
    int gid = blockIdx.x * blockDim.x + threadIdx.x;  // 0..B*H/4-1
    const float4* p4 = (const float4*)partials;
    float4 acc = {0.0f, 0.0f, 0.0f, 0.0f};
#pragma unroll
    for (int s = 0; s < SSPLIT; ++s) {
        float4 x = p4[(size_t)s * (BB * HH / 4) + gid];
        acc.x += x.x; acc.y += x.y; acc.z += x.z; acc.w += x.w;
    }
    ((float4*)c_t)[gid] = acc;
}

extern "C" void kernel_launch(void* const* d_in, const int* in_sizes, int n_in,
                              void* d_out, int out_size, void* d_ws, size_t ws_size,
                              hipStream_t stream)
{
    const float* s_t_hat  = (const float*)d_in[0];
    const float* enc_out  = (const float*)d_in[1];
    const float* enc_feat = (const float*)d_in[2];
    const float* mask     = (const float*)d_in[3];
    const float* cov      = (const float*)d_in[4];
    const float* W_dec    = (const float*)d_in[5];
    const float* b_dec    = (const float*)d_in[6];
    const float* W_c      = (const float*)d_in[7];
    const float* v        = (const float*)d_in[8];

    float* out    = (float*)d_out;
    float* c_t    = out;                    // B*H
    float* attn1  = out + BB * HH;          // B*S
    float* attn2  = attn1 + BB * SS;        // B*S
    float* scores = attn2 + BB * SS;        // B*S

    float* dec_fea  = (float*)d_ws;                 // B*H floats
    float* partials = dec_fea + BB * HH;            // SSPLIT*B*H floats (4 MB)

    dec_fea_kernel<<<dim3(BB * HH / 4), 256, 0, stream>>>(s_t_hat, W_dec, b_dec, dec_fea);
    scores_kernel<<<dim3(BB * SS / 4), 256, 0, stream>>>(enc_feat, dec_fea, cov, W_c, v, scores);
    softmax_kernel<<<dim3(BB), 1024, 0, stream>>>(scores, mask, attn1, attn2);
    context_partial_kernel<<<dim3(SSPLIT, BB), 256, 0, stream>>>(enc_out, attn1, partials);
    context_reduce_kernel<<<dim3(BB * HH / 1024), 256, 0, stream>>>(partials, c_t);
}